// Round 1
// baseline (3420.910 us; speedup 1.0000x reference)
//
#include <hip/hip_runtime.h>

#define N_NODES 50000
#define N_EDGES 1600000
#define IN_FEATS 128
#define N_HIDDEN 256
#define N_CLASSES 41

// -------- workspace layout (bytes) --------
// deg:  N_NODES f32                  @ 0
// acc0: N_NODES*IN_FEATS f32         @ ACC0_OFF
// y1:   N_NODES*N_CLASSES f32        @ Y1_OFF
#define DEG_BYTES   (N_NODES * 4)
#define ACC0_OFF    200192            // 512-aligned, >= DEG_BYTES
#define ACC0_BYTES  (N_NODES * IN_FEATS * 4)
#define Y1_OFF      (ACC0_OFF + ACC0_BYTES)

// degree: one thread per edge
__global__ void deg_kernel(const int* __restrict__ dst, float* __restrict__ deg) {
    int e = blockIdx.x * blockDim.x + threadIdx.x;
    if (e < N_EDGES) atomicAdd(&deg[dst[e]], 1.0f);
}

// layer-0 scatter: 32 threads per edge, float4 per thread
__global__ void scatter1(const float* __restrict__ feat, const int* __restrict__ src,
                         const int* __restrict__ dst, float* __restrict__ acc0) {
    long long idx = (long long)blockIdx.x * blockDim.x + threadIdx.x;
    if (idx >= (long long)N_EDGES * 32) return;
    int e  = (int)(idx >> 5);
    int c4 = (int)(idx & 31) << 2;          // float offset 0..124
    int s = src[e], d = dst[e];
    float4 v = *(const float4*)(feat + (long long)s * IN_FEATS + c4);
    float* p = acc0 + (long long)d * IN_FEATS + c4;
    atomicAdd(p + 0, v.x);
    atomicAdd(p + 1, v.y);
    atomicAdd(p + 2, v.z);
    atomicAdd(p + 3, v.w);
}

// fused: x = acc0[row]/deg ; h = relu(x@W1+b1) ; y1[row] = h@W2  (b2 added later)
__global__ __launch_bounds__(256) void mlp_kernel(
        const float* __restrict__ acc0, const float* __restrict__ deg,
        const float* __restrict__ W1, const float* __restrict__ b1,
        const float* __restrict__ W2, float* __restrict__ y1) {
    int row = blockIdx.x;
    int t = threadIdx.x;
    __shared__ float x[IN_FEATS];
    __shared__ float h[N_HIDDEN];
    float invd = 1.0f / fmaxf(deg[row], 1.0f);
    if (t < IN_FEATS) x[t] = acc0[(long long)row * IN_FEATS + t] * invd;
    __syncthreads();
    float acc = b1[t];
#pragma unroll 8
    for (int k = 0; k < IN_FEATS; ++k)
        acc = fmaf(x[k], W1[k * N_HIDDEN + t], acc);
    h[t] = fmaxf(acc, 0.0f);
    __syncthreads();
    if (t < N_CLASSES) {
        float acc2 = 0.0f;
#pragma unroll 8
        for (int k = 0; k < N_HIDDEN; ++k)
            acc2 = fmaf(h[k], W2[k * N_CLASSES + t], acc2);
        y1[(long long)row * N_CLASSES + t] = acc2;
    }
}

// layer-1 scatter on projected 41-dim rows: thread -> (edge, class)
__global__ void scatter_out(const float* __restrict__ y1, const int* __restrict__ src,
                            const int* __restrict__ dst, float* __restrict__ out) {
    long long idx = (long long)blockIdx.x * blockDim.x + threadIdx.x;
    if (idx >= (long long)N_EDGES * N_CLASSES) return;
    int e = (int)(idx / N_CLASSES);
    int c = (int)(idx - (long long)e * N_CLASSES);
    atomicAdd(&out[(long long)dst[e] * N_CLASSES + c],
              y1[(long long)src[e] * N_CLASSES + c]);
}

// out = out/deg + b2
__global__ void finalize(float* __restrict__ out, const float* __restrict__ deg,
                         const float* __restrict__ b2) {
    int idx = blockIdx.x * blockDim.x + threadIdx.x;
    if (idx >= N_NODES * N_CLASSES) return;
    int row = idx / N_CLASSES;
    int c = idx - row * N_CLASSES;
    out[idx] = out[idx] / fmaxf(deg[row], 1.0f) + b2[c];
}

extern "C" void kernel_launch(void* const* d_in, const int* in_sizes, int n_in,
                              void* d_out, int out_size, void* d_ws, size_t ws_size,
                              hipStream_t stream) {
    const float* feat = (const float*)d_in[0];
    const int*   src  = (const int*)d_in[1];
    const int*   dst  = (const int*)d_in[2];
    const float* W1   = (const float*)d_in[3];
    const float* b1   = (const float*)d_in[4];
    const float* W2   = (const float*)d_in[5];
    const float* b2   = (const float*)d_in[6];
    float* out = (float*)d_out;

    char* ws = (char*)d_ws;
    float* deg  = (float*)(ws);
    float* acc0 = (float*)(ws + ACC0_OFF);
    float* y1   = (float*)(ws + Y1_OFF);

    hipMemsetAsync(deg, 0, DEG_BYTES, stream);
    hipMemsetAsync(acc0, 0, ACC0_BYTES, stream);
    hipMemsetAsync(out, 0, (size_t)N_NODES * N_CLASSES * 4, stream);

    deg_kernel<<<(N_EDGES + 255) / 256, 256, 0, stream>>>(dst, deg);

    long long t1 = (long long)N_EDGES * 32;
    scatter1<<<(t1 + 255) / 256, 256, 0, stream>>>(feat, src, dst, acc0);

    mlp_kernel<<<N_NODES, 256, 0, stream>>>(acc0, deg, W1, b1, W2, y1);

    long long t2 = (long long)N_EDGES * N_CLASSES;
    scatter_out<<<(t2 + 255) / 256, 256, 0, stream>>>(y1, src, dst, out);

    finalize<<<(N_NODES * N_CLASSES + 255) / 256, 256, 0, stream>>>(out, deg, b2);
}

// Round 2
// 700.411 us; speedup vs baseline: 4.8841x; 4.8841x over previous
//
#include <hip/hip_runtime.h>

#define N_NODES 50000
#define N_EDGES 1600000
#define IN_FEATS 128
#define N_HIDDEN 256
#define N_CLASSES 41

// -------- workspace layout (bytes) --------
#define IDEG_OFF     0              // N_NODES int
#define ROWSTART_OFF 204800        // N_NODES+1 int
#define CURSOR_OFF   409600        // N_NODES int
#define EDGESRC_OFF  614400        // N_EDGES int  (6.4 MB)
#define Y1_OFF       7340032       // N_NODES*N_CLASSES f32 (8.2 MB)

#define SCAN_THREADS 1024
#define SCAN_CHUNK   ((N_NODES + SCAN_THREADS - 1) / SCAN_THREADS)   // 49

__global__ void deg_kernel(const int* __restrict__ dst, int* __restrict__ ideg) {
    int e = blockIdx.x * blockDim.x + threadIdx.x;
    if (e < N_EDGES) atomicAdd(&ideg[dst[e]], 1);
}

// single-block exclusive scan of ideg -> row_start (row_start[N_NODES] = N_EDGES)
__global__ __launch_bounds__(SCAN_THREADS) void scan_kernel(
        const int* __restrict__ ideg, int* __restrict__ row_start) {
    __shared__ int part[SCAN_THREADS];
    int t = threadIdx.x;
    int lo = t * SCAN_CHUNK;
    int hi = min(lo + SCAN_CHUNK, N_NODES);
    int s = 0;
    for (int i = lo; i < hi; ++i) s += ideg[i];
    part[t] = s;
    __syncthreads();
    // Hillis-Steele inclusive scan
    for (int off = 1; off < SCAN_THREADS; off <<= 1) {
        int v = (t >= off) ? part[t - off] : 0;
        __syncthreads();
        if (t >= off) part[t] += v;
        __syncthreads();
    }
    int run = (t == 0) ? 0 : part[t - 1];
    for (int i = lo; i < hi; ++i) {
        row_start[i] = run;
        run += ideg[i];
    }
    if (t == SCAN_THREADS - 1) row_start[N_NODES] = part[SCAN_THREADS - 1];
}

// bucket edges by dst: edge_src[row_start[d] + pos] = src[e]
__global__ void fill_csr(const int* __restrict__ src, const int* __restrict__ dst,
                         const int* __restrict__ row_start, int* __restrict__ cursor,
                         int* __restrict__ edge_src) {
    int e = blockIdx.x * blockDim.x + threadIdx.x;
    if (e >= N_EDGES) return;
    int d = dst[e];
    int p = atomicAdd(&cursor[d], 1);
    edge_src[row_start[d] + p] = src[e];
}

// fused: for 4 nodes/block — gather mean of neighbor features (one wave/node),
// then h = relu(x@W1+b1), then y1 = h@W2  (b2 deferred to agg1)
#define NPB 4
__global__ __launch_bounds__(256) void agg0_mlp(
        const float* __restrict__ feat, const int* __restrict__ row_start,
        const int* __restrict__ edge_src,
        const float* __restrict__ W1, const float* __restrict__ b1,
        const float* __restrict__ W2, float* __restrict__ y1) {
    __shared__ float xs[NPB][IN_FEATS];
    __shared__ float hs[NPB][N_HIDDEN];
    int t = threadIdx.x;
    int wave = t >> 6;          // 0..3
    int lane = t & 63;
    int node = blockIdx.x * NPB + wave;

    // ---- gather phase: one wave per node, lane owns 2 feats (float2) ----
    int start = row_start[node];
    int end   = row_start[node + 1];
    float2 s = make_float2(0.0f, 0.0f);
    for (int i = start; i < end; ++i) {
        int sn = edge_src[i];
        float2 v = *(const float2*)(feat + (long long)sn * IN_FEATS + lane * 2);
        s.x += v.x; s.y += v.y;
    }
    float invd = 1.0f / fmaxf((float)(end - start), 1.0f);
    xs[wave][lane * 2 + 0] = s.x * invd;
    xs[wave][lane * 2 + 1] = s.y * invd;
    __syncthreads();

    // ---- GEMM1: each thread owns hidden unit t for all 4 nodes ----
    float a0 = b1[t], a1 = a0, a2 = a0, a3 = a0;
#pragma unroll 8
    for (int k = 0; k < IN_FEATS; ++k) {
        float w = W1[k * N_HIDDEN + t];
        a0 = fmaf(xs[0][k], w, a0);
        a1 = fmaf(xs[1][k], w, a1);
        a2 = fmaf(xs[2][k], w, a2);
        a3 = fmaf(xs[3][k], w, a3);
    }
    hs[0][t] = fmaxf(a0, 0.0f);
    hs[1][t] = fmaxf(a1, 0.0f);
    hs[2][t] = fmaxf(a2, 0.0f);
    hs[3][t] = fmaxf(a3, 0.0f);
    __syncthreads();

    // ---- GEMM2: threads 0..163 -> (node n, class c) ----
    if (t < NPB * N_CLASSES) {
        int n = t / N_CLASSES;
        int c = t - n * N_CLASSES;
        float acc = 0.0f;
#pragma unroll 8
        for (int k = 0; k < N_HIDDEN; ++k)
            acc = fmaf(hs[n][k], W2[k * N_CLASSES + c], acc);
        y1[(long long)(blockIdx.x * NPB + n) * N_CLASSES + c] = acc;
    }
}

// layer-1 aggregation: one wave per node gathers y1 rows; out = sum/deg + b2
__global__ __launch_bounds__(256) void agg1(
        const float* __restrict__ y1, const int* __restrict__ row_start,
        const int* __restrict__ edge_src, const float* __restrict__ b2,
        float* __restrict__ out) {
    int t = threadIdx.x;
    int wave = t >> 6;
    int lane = t & 63;
    int node = blockIdx.x * 4 + wave;
    if (lane >= N_CLASSES) return;
    int start = row_start[node];
    int end   = row_start[node + 1];
    float s = 0.0f;
    for (int i = start; i < end; ++i) {
        int sn = edge_src[i];
        s += y1[(long long)sn * N_CLASSES + lane];
    }
    float invd = 1.0f / fmaxf((float)(end - start), 1.0f);
    out[(long long)node * N_CLASSES + lane] = s * invd + b2[lane];
}

extern "C" void kernel_launch(void* const* d_in, const int* in_sizes, int n_in,
                              void* d_out, int out_size, void* d_ws, size_t ws_size,
                              hipStream_t stream) {
    const float* feat = (const float*)d_in[0];
    const int*   src  = (const int*)d_in[1];
    const int*   dst  = (const int*)d_in[2];
    const float* W1   = (const float*)d_in[3];
    const float* b1   = (const float*)d_in[4];
    const float* W2   = (const float*)d_in[5];
    const float* b2   = (const float*)d_in[6];
    float* out = (float*)d_out;

    char* ws = (char*)d_ws;
    int*   ideg      = (int*)(ws + IDEG_OFF);
    int*   row_start = (int*)(ws + ROWSTART_OFF);
    int*   cursor    = (int*)(ws + CURSOR_OFF);
    int*   edge_src  = (int*)(ws + EDGESRC_OFF);
    float* y1        = (float*)(ws + Y1_OFF);

    hipMemsetAsync(ideg, 0, N_NODES * 4, stream);
    hipMemsetAsync(cursor, 0, N_NODES * 4, stream);

    deg_kernel<<<(N_EDGES + 255) / 256, 256, 0, stream>>>(dst, ideg);
    scan_kernel<<<1, SCAN_THREADS, 0, stream>>>(ideg, row_start);
    fill_csr<<<(N_EDGES + 255) / 256, 256, 0, stream>>>(src, dst, row_start, cursor, edge_src);

    agg0_mlp<<<N_NODES / NPB, 256, 0, stream>>>(feat, row_start, edge_src, W1, b1, W2, y1);
    agg1<<<N_NODES / 4, 256, 0, stream>>>(y1, row_start, edge_src, b2, out);
}

// Round 3
// 612.486 us; speedup vs baseline: 5.5853x; 1.1436x over previous
//
#include <hip/hip_runtime.h>

#define N_NODES 50000
#define N_EDGES 1600000
#define IN_FEATS 128
#define N_HIDDEN 256
#define N_CLASSES 41
#define Y1_STRIDE 48          // 41 padded -> 192B rows, 64B-aligned

// -------- workspace layout (bytes) --------
#define IDEG_OFF     0              // N_NODES int
#define ROWSTART_OFF 204800         // N_NODES+1 int
#define CURSOR_OFF   409600         // N_NODES int
#define EDGESRC_OFF  614400         // N_EDGES int (6.4 MB)
#define Y1_OFF       7014400        // N_NODES*Y1_STRIDE f32 (9.6 MB)

#define SCAN_THREADS 1024
#define SCAN_CHUNK   ((N_NODES + SCAN_THREADS - 1) / SCAN_THREADS)   // 49

__global__ void deg_kernel(const int* __restrict__ dst, int* __restrict__ ideg) {
    int e = blockIdx.x * blockDim.x + threadIdx.x;
    if (e < N_EDGES) atomicAdd(&ideg[dst[e]], 1);
}

// single-block exclusive scan of ideg -> row_start (row_start[N_NODES] = N_EDGES)
__global__ __launch_bounds__(SCAN_THREADS) void scan_kernel(
        const int* __restrict__ ideg, int* __restrict__ row_start) {
    __shared__ int part[SCAN_THREADS];
    int t = threadIdx.x;
    int lo = t * SCAN_CHUNK;
    int hi = min(lo + SCAN_CHUNK, N_NODES);
    int s = 0;
    for (int i = lo; i < hi; ++i) s += ideg[i];
    part[t] = s;
    __syncthreads();
    for (int off = 1; off < SCAN_THREADS; off <<= 1) {
        int v = (t >= off) ? part[t - off] : 0;
        __syncthreads();
        if (t >= off) part[t] += v;
        __syncthreads();
    }
    int run = (t == 0) ? 0 : part[t - 1];
    for (int i = lo; i < hi; ++i) {
        row_start[i] = run;
        run += ideg[i];
    }
    if (t == SCAN_THREADS - 1) row_start[N_NODES] = part[SCAN_THREADS - 1];
}

// bucket edges by dst; cursor pre-initialized to row_start (d2d copy)
__global__ void fill_csr(const int* __restrict__ src, const int* __restrict__ dst,
                         int* __restrict__ cursor, int* __restrict__ edge_src) {
    int e = blockIdx.x * blockDim.x + threadIdx.x;
    if (e >= N_EDGES) return;
    int d = dst[e];
    int p = atomicAdd(&cursor[d], 1);
    edge_src[p] = src[e];
}

// fused: 8 nodes/block (one wave gathers per node), then relu(x@W1+b1)@W2
#define NPB 8
__global__ __launch_bounds__(512) void agg0_mlp(
        const float* __restrict__ feat, const int* __restrict__ row_start,
        const int* __restrict__ edge_src,
        const float* __restrict__ W1, const float* __restrict__ b1,
        const float* __restrict__ W2, float* __restrict__ y1) {
    __shared__ float xs[NPB][IN_FEATS];
    __shared__ float hs[NPB][N_HIDDEN];
    const int t = threadIdx.x;
    const int wave = t >> 6, lane = t & 63;
    const int half = lane >> 5, l31 = lane & 31;
    const int node = blockIdx.x * NPB + wave;

    const int start = row_start[node];
    const int deg = row_start[node + 1] - start;

    // ---- gather: 2 edges/iter (half-wave each, float4/lane), 8 loads in flight ----
    float4 acc = make_float4(0.f, 0.f, 0.f, 0.f);
    for (int base = 0; base < deg; base += 64) {
        int cnt = deg - base; if (cnt > 64) cnt = 64;
        int myIdx = 0;
        if (lane < cnt) myIdx = edge_src[start + base + lane];   // coalesced batch
        for (int j = 0; j < cnt; j += 8) {
#pragma unroll
            for (int u = 0; u < 4; ++u) {
                int e = j + 2 * u + half;
                int sn = __shfl(myIdx, e);
                if (e < cnt) {
                    const float4 v = *(const float4*)(feat + ((size_t)sn << 7) + (l31 << 2));
                    acc.x += v.x; acc.y += v.y; acc.z += v.z; acc.w += v.w;
                }
            }
        }
    }
    // combine the two half-wave partial sums (same columns, disjoint edges)
    acc.x += __shfl_xor(acc.x, 32);
    acc.y += __shfl_xor(acc.y, 32);
    acc.z += __shfl_xor(acc.z, 32);
    acc.w += __shfl_xor(acc.w, 32);
    if (half == 0) {
        float invd = 1.0f / fmaxf((float)deg, 1.0f);
        float4* xp = (float4*)&xs[wave][l31 << 2];
        *xp = make_float4(acc.x * invd, acc.y * invd, acc.z * invd, acc.w * invd);
    }
    __syncthreads();

    // ---- GEMM1: thread owns hidden unit (t&255) for 4 nodes ----
    const int unit = t & 255;
    const int g = (t >> 8) << 2;          // 0 or 4
    float c0 = b1[unit];
    float c1 = c0, c2 = c0, c3 = c0;
#pragma unroll 8
    for (int k = 0; k < IN_FEATS; ++k) {
        float w = W1[k * N_HIDDEN + unit];
        c0 = fmaf(xs[g + 0][k], w, c0);
        c1 = fmaf(xs[g + 1][k], w, c1);
        c2 = fmaf(xs[g + 2][k], w, c2);
        c3 = fmaf(xs[g + 3][k], w, c3);
    }
    hs[g + 0][unit] = fmaxf(c0, 0.f);
    hs[g + 1][unit] = fmaxf(c1, 0.f);
    hs[g + 2][unit] = fmaxf(c2, 0.f);
    hs[g + 3][unit] = fmaxf(c3, 0.f);
    __syncthreads();

    // ---- GEMM2: threads 0..327 -> (node n, class c) ----
    if (t < NPB * N_CLASSES) {
        int n = t / N_CLASSES;
        int c = t - n * N_CLASSES;
        float s = 0.f;
#pragma unroll 8
        for (int k = 0; k < N_HIDDEN; ++k)
            s = fmaf(hs[n][k], W2[k * N_CLASSES + c], s);
        y1[(size_t)(blockIdx.x * NPB + n) * Y1_STRIDE + c] = s;
    }
}

// layer-1 aggregation: one wave per node, preloaded indices, 4 rows in flight
__global__ __launch_bounds__(256) void agg1(
        const float* __restrict__ y1, const int* __restrict__ row_start,
        const int* __restrict__ edge_src, const float* __restrict__ b2,
        float* __restrict__ out) {
    const int t = threadIdx.x;
    const int wave = t >> 6, lane = t & 63;
    const int node = blockIdx.x * 4 + wave;
    const int start = row_start[node];
    const int deg = row_start[node + 1] - start;
    float s = 0.f;
    for (int base = 0; base < deg; base += 64) {
        int cnt = deg - base; if (cnt > 64) cnt = 64;
        int myIdx = 0;
        if (lane < cnt) myIdx = edge_src[start + base + lane];
        for (int j = 0; j < cnt; j += 4) {
#pragma unroll
            for (int u = 0; u < 4; ++u) {
                int e = j + u;
                int sn = __shfl(myIdx, e);
                if (e < cnt && lane < N_CLASSES)
                    s += y1[(size_t)sn * Y1_STRIDE + lane];
            }
        }
    }
    if (lane < N_CLASSES) {
        float invd = 1.0f / fmaxf((float)deg, 1.0f);
        out[(size_t)node * N_CLASSES + lane] = s * invd + b2[lane];
    }
}

extern "C" void kernel_launch(void* const* d_in, const int* in_sizes, int n_in,
                              void* d_out, int out_size, void* d_ws, size_t ws_size,
                              hipStream_t stream) {
    const float* feat = (const float*)d_in[0];
    const int*   src  = (const int*)d_in[1];
    const int*   dst  = (const int*)d_in[2];
    const float* W1   = (const float*)d_in[3];
    const float* b1   = (const float*)d_in[4];
    const float* W2   = (const float*)d_in[5];
    const float* b2   = (const float*)d_in[6];
    float* out = (float*)d_out;

    char* ws = (char*)d_ws;
    int*   ideg      = (int*)(ws + IDEG_OFF);
    int*   row_start = (int*)(ws + ROWSTART_OFF);
    int*   cursor    = (int*)(ws + CURSOR_OFF);
    int*   edge_src  = (int*)(ws + EDGESRC_OFF);
    float* y1        = (float*)(ws + Y1_OFF);

    hipMemsetAsync(ideg, 0, N_NODES * 4, stream);

    deg_kernel<<<(N_EDGES + 255) / 256, 256, 0, stream>>>(dst, ideg);
    scan_kernel<<<1, SCAN_THREADS, 0, stream>>>(ideg, row_start);
    hipMemcpyAsync(cursor, row_start, N_NODES * 4, hipMemcpyDeviceToDevice, stream);
    fill_csr<<<(N_EDGES + 255) / 256, 256, 0, stream>>>(src, dst, cursor, edge_src);

    agg0_mlp<<<N_NODES / NPB, 512, 0, stream>>>(feat, row_start, edge_src, W1, b1, W2, y1);
    agg1<<<N_NODES / 4, 256, 0, stream>>>(y1, row_start, edge_src, b2, out);
}